// Round 8
// baseline (59.030 us; speedup 1.0000x reference)
//
#include <hip/hip_runtime.h>

// LIF forward: x [T=32, B=64, N=16384] f32 -> spikes (0/1) f32, same shape.
// mem_t = mem_{t-1}*0.25 + x_t ; s_t = (mem_t > 1) ; reset mem on spike.
// Bit-exact vs numpy.
//
// R7 post-mortem: all structures (interleaved / phase-split, occupancy
// 28-67%) land in 48-52 us -> NOT latency-bound. Combined L2-fabric
// traffic is 265 MB/replay; best (R4) = 5.6 TB/s = 88% of the 6.3 TB/s
// copy ceiling -> mixed-stream BW wall. Back to R4's best structure
// (f32x2 interleaved, 2048 blocks) + ONE lever: non-temporal loads so
// the zero-reuse x stream doesn't allocate in L2, freeing L2 for write
// buffering. Decisive readout: FETCH_SIZE ~65 MB = L2-only bypass
// (keep); ~131 MB = MALL bypassed too (revert).

typedef float f32x2 __attribute__((ext_vector_type(2)));

__global__ __launch_bounds__(256) void lif_fwd_kernel(
    const f32x2* __restrict__ x, f32x2* __restrict__ out, int BN2, int T) {
    const int i = blockIdx.x * blockDim.x + threadIdx.x;
    if (i >= BN2) return;

    const f32x2* xp = x + i;
    f32x2* op = out + i;

    float mx = 0.f, my = 0.f;

    #pragma unroll 32
    for (int t = 0; t < T; ++t) {
        const f32x2 xt = __builtin_nontemporal_load(&xp[(size_t)t * (size_t)BN2]);

        f32x2 s;
        mx = mx * 0.25f + xt.x;
        my = my * 0.25f + xt.y;

        s.x = (mx > 1.0f) ? 1.0f : 0.0f;
        s.y = (my > 1.0f) ? 1.0f : 0.0f;

        mx = (s.x != 0.0f) ? 0.0f : mx;
        my = (s.y != 0.0f) ? 0.0f : my;

        op[(size_t)t * (size_t)BN2] = s;
    }
}

extern "C" void kernel_launch(void* const* d_in, const int* in_sizes, int n_in,
                              void* d_out, int out_size, void* d_ws, size_t ws_size,
                              hipStream_t stream) {
    const float* x = (const float*)d_in[0];
    float* out = (float*)d_out;

    const int T = 32;
    const int total = in_sizes[0];        // 33,554,432
    const int BN = total / T;             // 1,048,576
    const int BN2 = BN / 2;               // 524,288

    const int block = 256;
    const int grid = (BN2 + block - 1) / block;  // 2048

    lif_fwd_kernel<<<grid, block, 0, stream>>>(
        (const f32x2*)x, (f32x2*)out, BN2, T);
}

// Round 9
// 43.221 us; speedup vs baseline: 1.3658x; 1.3658x over previous
//
#include <hip/hip_runtime.h>

// LIF forward: x [T=32, B=64, N=16384] f32 -> spikes (0/1) f32, same shape.
// mem_t = mem_{t-1}*0.25 + x_t ; s_t = (mem_t > 1) ; reset mem on spike.
// Bit-exact vs numpy.
//
// FINAL (revert of R8's NT-load experiment). Session findings:
// - R3: NT stores: no FETCH change (MALL is memory-side; write stream
//   displaces x regardless). Neutral-to-worse.
// - R8: NT loads: bypass MALL allocation for reads -> lose the ~68 MB/replay
//   L3 read absorption -> 59 us. Reverted.
// - R5-R7: latency/MLP theory refuted: occupancy 28-67%, phase-split vs
//   interleaved, all land 48-52 us. Not latency-bound.
// - Best: this structure (f32x2, 2048 blocks, interleaved) = 47.7 us =
//   268 MB app traffic at 5.6 TB/s combined = ~89% of the 6.3 TB/s
//   measured mixed read+write D2D ceiling. Structural floor: 134 MB read
//   + 134 MB f32 write, both mandatory.

typedef float f32x2 __attribute__((ext_vector_type(2)));

__global__ __launch_bounds__(256) void lif_fwd_kernel(
    const f32x2* __restrict__ x, f32x2* __restrict__ out, int BN2, int T) {
    const int i = blockIdx.x * blockDim.x + threadIdx.x;
    if (i >= BN2) return;

    const f32x2* xp = x + i;
    f32x2* op = out + i;

    float mx = 0.f, my = 0.f;

    #pragma unroll 32
    for (int t = 0; t < T; ++t) {
        const f32x2 xt = xp[(size_t)t * (size_t)BN2];

        f32x2 s;
        mx = mx * 0.25f + xt.x;
        my = my * 0.25f + xt.y;

        s.x = (mx > 1.0f) ? 1.0f : 0.0f;
        s.y = (my > 1.0f) ? 1.0f : 0.0f;

        mx = (s.x != 0.0f) ? 0.0f : mx;
        my = (s.y != 0.0f) ? 0.0f : my;

        op[(size_t)t * (size_t)BN2] = s;
    }
}

extern "C" void kernel_launch(void* const* d_in, const int* in_sizes, int n_in,
                              void* d_out, int out_size, void* d_ws, size_t ws_size,
                              hipStream_t stream) {
    const float* x = (const float*)d_in[0];
    float* out = (float*)d_out;

    const int T = 32;
    const int total = in_sizes[0];        // 33,554,432
    const int BN = total / T;             // 1,048,576
    const int BN2 = BN / 2;               // 524,288

    const int block = 256;
    const int grid = (BN2 + block - 1) / block;  // 2048

    lif_fwd_kernel<<<grid, block, 0, stream>>>(
        (const f32x2*)x, (f32x2*)out, BN2, T);
}